// Round 9
// baseline (98.807 us; speedup 1.0000x reference)
//
#include <hip/hip_runtime.h>

namespace {

constexpr int NCLS   = 20;
constexpr int NIMG   = 16384;
constexpr int NCELLS = NIMG * 7 * 7;       // 802816
constexpr int BLOCK  = 256;
constexpr int NBLK   = NCELLS / 2 / BLOCK; // 1568 exactly (2 cells/thread)

typedef float vfloat4 __attribute__((ext_vector_type(4)));  // native vector:
// HIP's float4 is a class; __builtin_nontemporal_load requires a native type.

__device__ __forceinline__ float cell_loss(const float* __restrict__ p,
                                           const float* __restrict__ l) {
  const float l4 = l[4];
  if (!(l4 > 0.0f)) {
    // no-object cell: 0.5 * sum over both conf channels
    float d4 = p[4] - l4;
    float d9 = p[9] - l[9];
    return 0.5f * (d4 * d4 + d9 * d9);
  }
  const float sc = 1.0f / 7.0f;
  // ground-truth corners from label box 0
  float gcx = l[0] * sc, gcy = l[1] * sc, gw = l[2], gh = l[3];
  float gx1 = gcx - 0.5f * gw, gy1 = gcy - 0.5f * gh;
  float gx2 = gcx + 0.5f * gw, gy2 = gcy + 0.5f * gh;
  float a2 = (gx2 - gx1) * (gy2 - gy1);

  float iou0 = 0.0f, iou1 = 0.0f;
#pragma unroll
  for (int b = 0; b < 2; ++b) {
    const float* bp = p + 5 * b;
    float cx = bp[0] * sc, cy = bp[1] * sc, w = bp[2], h = bp[3];
    float x1 = cx - 0.5f * w, y1 = cy - 0.5f * h;
    float x2 = cx + 0.5f * w, y2 = cy + 0.5f * h;
    float ix1 = fmaxf(x1, gx1), iy1 = fmaxf(y1, gy1);
    float ix2 = fminf(x2, gx2), iy2 = fminf(y2, gy2);
    float inter = fmaxf(ix2 - ix1, 0.0f) * fmaxf(iy2 - iy1, 0.0f);
    float a1 = (x2 - x1) * (y2 - y1);
    float v = inter / (a1 + a2 - inter);
    if (b == 0) iou0 = v; else iou1 = v;
  }
  // argmax with tie -> box 0 (jnp.argmax semantics)
  int r = (iou1 > iou0) ? 1 : 0;
  float miou = fmaxf(iou0, iou1);
  const float* rp = p + 5 * r;
  const float* rl = l + 5 * r;

  float dx = rp[0] - rl[0], dy = rp[1] - rl[1];
  float xy = dx * dx + dy * dy;
  float dw = sqrtf(rp[2]) - sqrtf(rl[2]);
  float dh = sqrtf(rp[3]) - sqrtf(rl[3]);
  float wh = dw * dw + dh * dh;
  float dr = rp[4] - miou;            // response conf vs max IoU
  float nr = p[5 * (1 - r) + 4];      // non-responsible conf
  float cls = 0.0f;
#pragma unroll
  for (int c = 0; c < NCLS; ++c) {
    float d = p[10 + c] - l[10 + c];
    cls = fmaf(d, d, cls);
  }
  return 5.0f * (xy + wh) + 2.0f * (dr * dr) + nr * nr + cls;
}

// R7 structure + NON-TEMPORAL input loads (global_load_dwordx4 nt): the
// 193 MB zero-reuse stream churns the 32 MB aggregate L2 ~6x per pass;
// nt marks lines evict-first/no-allocate, removing fill/eviction-pipeline
// serialization (the hypothesized ~4.3 TB/s wall).
__global__ __launch_bounds__(BLOCK) void yolo_loss_main(
    const float* __restrict__ preds, const float* __restrict__ labels,
    float* __restrict__ out) {
  __shared__ float wsum[BLOCK / 64];

  const int t = threadIdx.x;
  const long long g = (long long)blockIdx.x * BLOCK + t;  // pair index
  // Each thread owns 2 adjacent cells = 60 floats = 240 B (16B-aligned).
  const vfloat4* gp4 = reinterpret_cast<const vfloat4*>(preds) + g * 15;
  const vfloat4* gl4 = reinterpret_cast<const vfloat4*>(labels) + g * 15;

  float p[60], l[60];
#pragma unroll
  for (int k = 0; k < 15; ++k) {
    vfloat4 vp = __builtin_nontemporal_load(gp4 + k);
    vfloat4 vl = __builtin_nontemporal_load(gl4 + k);
    p[4 * k] = vp.x; p[4 * k + 1] = vp.y; p[4 * k + 2] = vp.z; p[4 * k + 3] = vp.w;
    l[4 * k] = vl.x; l[4 * k + 1] = vl.y; l[4 * k + 2] = vl.z; l[4 * k + 3] = vl.w;
  }

  float v = cell_loss(p, l) + cell_loss(p + 30, l + 30);

  // wave64 shuffle reduction, then cross-wave via tiny LDS
#pragma unroll
  for (int off = 32; off > 0; off >>= 1) v += __shfl_down(v, off);
  if ((t & 63) == 0) wsum[t >> 6] = v;
  __syncthreads();
  if (t == 0) {
    float bs = (wsum[0] + wsum[1]) + (wsum[2] + wsum[3]);
    // 1568 float atomics of ~0.05 onto a ~73 total: error ~1e-3 << 1.46 thr.
    atomicAdd(out, bs * (1.0f / (float)NIMG));
  }
}

}  // namespace

extern "C" void kernel_launch(void* const* d_in, const int* in_sizes, int n_in,
                              void* d_out, int out_size, void* d_ws, size_t ws_size,
                              hipStream_t stream) {
  const float* preds  = (const float*)d_in[0];
  const float* labels = (const float*)d_in[1];
  // d_out is poisoned once and never re-poisoned between replays: zero it
  // every launch so the accumulation is deterministic.
  (void)hipMemsetAsync(d_out, 0, sizeof(float), stream);
  yolo_loss_main<<<NBLK, BLOCK, 0, stream>>>(preds, labels, (float*)d_out);
}

// Round 10
// 46.278 us; speedup vs baseline: 2.1351x; 2.1351x over previous
//
#include <hip/hip_runtime.h>

namespace {

constexpr int NCLS   = 20;
constexpr int NIMG   = 16384;
constexpr int NCELLS = NIMG * 7 * 7;       // 802816
constexpr int BLOCK  = 256;
constexpr int NBLK   = NCELLS / 2 / BLOCK; // 1568 exactly (2 cells/thread)

__device__ __forceinline__ float cell_loss(const float* __restrict__ p,
                                           const float* __restrict__ l) {
  const float l4 = l[4];
  if (!(l4 > 0.0f)) {
    // no-object cell: 0.5 * sum over both conf channels
    float d4 = p[4] - l4;
    float d9 = p[9] - l[9];
    return 0.5f * (d4 * d4 + d9 * d9);
  }
  const float sc = 1.0f / 7.0f;
  // ground-truth corners from label box 0
  float gcx = l[0] * sc, gcy = l[1] * sc, gw = l[2], gh = l[3];
  float gx1 = gcx - 0.5f * gw, gy1 = gcy - 0.5f * gh;
  float gx2 = gcx + 0.5f * gw, gy2 = gcy + 0.5f * gh;
  float a2 = (gx2 - gx1) * (gy2 - gy1);

  float iou0 = 0.0f, iou1 = 0.0f;
#pragma unroll
  for (int b = 0; b < 2; ++b) {
    const float* bp = p + 5 * b;
    float cx = bp[0] * sc, cy = bp[1] * sc, w = bp[2], h = bp[3];
    float x1 = cx - 0.5f * w, y1 = cy - 0.5f * h;
    float x2 = cx + 0.5f * w, y2 = cy + 0.5f * h;
    float ix1 = fmaxf(x1, gx1), iy1 = fmaxf(y1, gy1);
    float ix2 = fminf(x2, gx2), iy2 = fminf(y2, gy2);
    float inter = fmaxf(ix2 - ix1, 0.0f) * fmaxf(iy2 - iy1, 0.0f);
    float a1 = (x2 - x1) * (y2 - y1);
    float v = inter / (a1 + a2 - inter);
    if (b == 0) iou0 = v; else iou1 = v;
  }
  // argmax with tie -> box 0 (jnp.argmax semantics)
  int r = (iou1 > iou0) ? 1 : 0;
  float miou = fmaxf(iou0, iou1);
  const float* rp = p + 5 * r;
  const float* rl = l + 5 * r;

  float dx = rp[0] - rl[0], dy = rp[1] - rl[1];
  float xy = dx * dx + dy * dy;
  float dw = sqrtf(rp[2]) - sqrtf(rl[2]);
  float dh = sqrtf(rp[3]) - sqrtf(rl[3]);
  float wh = dw * dw + dh * dh;
  float dr = rp[4] - miou;            // response conf vs max IoU
  float nr = p[5 * (1 - r) + 4];      // non-responsible conf
  float cls = 0.0f;
#pragma unroll
  for (int c = 0; c < NCLS; ++c) {
    float d = p[10 + c] - l[10 + c];
    cls = fmaf(d, d, cls);
  }
  return 5.0f * (xy + wh) + 2.0f * (dr * dr) + nr * nr + cls;
}

// Best-measured structure (R7, 46.65 us): per-thread 240B register chunks
// (cached float4 loads — nt regressed 2.1x, R9), wave64 shuffle reduce, one
// pre-scaled float atomic per block straight into out[0]. Single worker
// dispatch + 4B memset. ~4.3 TB/s effective read — the measured service
// ceiling for this stream across 8 structure/policy variants.
__global__ __launch_bounds__(BLOCK) void yolo_loss_main(
    const float* __restrict__ preds, const float* __restrict__ labels,
    float* __restrict__ out) {
  __shared__ float wsum[BLOCK / 64];

  const int t = threadIdx.x;
  const long long g = (long long)blockIdx.x * BLOCK + t;  // pair index
  // Each thread owns 2 adjacent cells = 60 floats = 240 B (16B-aligned).
  const float4* gp4 = reinterpret_cast<const float4*>(preds) + g * 15;
  const float4* gl4 = reinterpret_cast<const float4*>(labels) + g * 15;

  float p[60], l[60];
#pragma unroll
  for (int k = 0; k < 15; ++k) {
    float4 vp = gp4[k];
    float4 vl = gl4[k];
    p[4 * k] = vp.x; p[4 * k + 1] = vp.y; p[4 * k + 2] = vp.z; p[4 * k + 3] = vp.w;
    l[4 * k] = vl.x; l[4 * k + 1] = vl.y; l[4 * k + 2] = vl.z; l[4 * k + 3] = vl.w;
  }

  float v = cell_loss(p, l) + cell_loss(p + 30, l + 30);

  // wave64 shuffle reduction, then cross-wave via tiny LDS
#pragma unroll
  for (int off = 32; off > 0; off >>= 1) v += __shfl_down(v, off);
  if ((t & 63) == 0) wsum[t >> 6] = v;
  __syncthreads();
  if (t == 0) {
    float bs = (wsum[0] + wsum[1]) + (wsum[2] + wsum[3]);
    // 1568 float atomics of ~0.05 onto a ~73 total: error ~1e-3 << 1.46 thr.
    atomicAdd(out, bs * (1.0f / (float)NIMG));
  }
}

}  // namespace

extern "C" void kernel_launch(void* const* d_in, const int* in_sizes, int n_in,
                              void* d_out, int out_size, void* d_ws, size_t ws_size,
                              hipStream_t stream) {
  const float* preds  = (const float*)d_in[0];
  const float* labels = (const float*)d_in[1];
  // d_out is poisoned once and never re-poisoned between replays: zero it
  // every launch so the accumulation is deterministic.
  (void)hipMemsetAsync(d_out, 0, sizeof(float), stream);
  yolo_loss_main<<<NBLK, BLOCK, 0, stream>>>(preds, labels, (float*)d_out);
}